// Round 1
// baseline (216.127 us; speedup 1.0000x reference)
//
#include <hip/hip_runtime.h>

#define FFT_N 8192
#define LOG_N 13
#define THREADS 512
#define PI_F 3.14159265358979323846f

// DST-II of each row of a (4096, 8192) fp32 matrix, mirroring the reference:
//   x2[n]  = x[n] * (-1)^n
//   v      = concat(x2[0::2], reverse(x2[1::2]))          (Makhoul reorder)
//   V      = FFT_8192(v)
//   dct[k] = Re(V[k] * exp(-i*pi*k/(2N)))
//   out[o] = dct[N-1-o]
__global__ __launch_bounds__(THREADS) void dst_fft_kernel(const float* __restrict__ x,
                                                          float* __restrict__ out) {
    __shared__ float2 buf[FFT_N];  // 64 KiB

    const int row = blockIdx.x;
    const float* __restrict__ xr = x + (size_t)row * FFT_N;
    float* __restrict__ yr = out + (size_t)row * FFT_N;
    const int tid = threadIdx.x;

    // ---- load, fused sign * Makhoul reorder ----
    // n even: v[n>>1] = x[n];  n odd: v[(16383-n)>>1] = -x[n]
#pragma unroll
    for (int s = 0; s < FFT_N / THREADS; ++s) {
        int n = tid + s * THREADS;
        float val = xr[n];
        int odd = n & 1;
        int idx = odd ? ((2 * FFT_N - 1 - n) >> 1) : (n >> 1);
        float sv = odd ? -val : val;
        buf[idx] = make_float2(sv, 0.0f);
    }
    __syncthreads();

    // ---- in-place radix-2 DIF FFT (output bit-reversed) ----
    for (int m = FFT_N >> 1; m >= 1; m >>= 1) {
        const float neg_pi_over_m = -PI_F / (float)m;  // exact: /2^k
#pragma unroll
        for (int b = 0; b < (FFT_N / 2) / THREADS; ++b) {
            int tt = tid + b * THREADS;
            int j = tt & (m - 1);
            int i0 = ((tt ^ j) << 1) | j;  // insert 0 at bit log2(m)
            int i1 = i0 + m;
            float2 a = buf[i0];
            float2 c = buf[i1];
            float sr = a.x + c.x, si = a.y + c.y;
            float dr = a.x - c.x, di = a.y - c.y;
            float ang = neg_pi_over_m * (float)j;  // in (-pi, 0]
            float sw, cw;
            __sincosf(ang, &sw, &cw);
            buf[i0] = make_float2(sr, si);
            buf[i1] = make_float2(dr * cw - di * sw, dr * sw + di * cw);
        }
        __syncthreads();
    }

    // ---- epilogue: twiddle by expk, un-bit-reverse, reverse output order ----
    // out[o] = Re(V[k] * exp(-i*phi)),  k = N-1-o,  phi = pi*k/(2N)
    //        = Vr*cos(phi) + Vi*sin(phi),  V[k] = buf[bitrev13(k)]
    const float phi_scale = PI_F / (2.0f * (float)FFT_N);
#pragma unroll
    for (int s = 0; s < FFT_N / THREADS; ++s) {
        int o = tid + s * THREADS;
        int k = (FFT_N - 1) - o;
        int r = (int)(__brev((unsigned int)k) >> (32 - LOG_N));
        float2 V = buf[r];
        float phi = phi_scale * (float)k;
        float sp, cp;
        __sincosf(phi, &sp, &cp);
        yr[o] = V.x * cp + V.y * sp;
    }
}

extern "C" void kernel_launch(void* const* d_in, const int* in_sizes, int n_in,
                              void* d_out, int out_size, void* d_ws, size_t ws_size,
                              hipStream_t stream) {
    const float* x = (const float*)d_in[0];
    float* out = (float*)d_out;
    const int rows = in_sizes[0] / FFT_N;  // 4096
    dst_fft_kernel<<<rows, THREADS, 0, stream>>>(x, out);
}

// Round 2
// 65.664 us; speedup vs baseline: 3.2914x; 3.2914x over previous
//
#include <hip/hip_runtime.h>

#define FFT_N 8192
#define THREADS 512
#define PI_F 3.14159265358979323846f
#define RT2O2 0.70710678118654752440f

struct cpx { float x, y; };

__device__ __forceinline__ cpx operator+(cpx a, cpx b) { return {a.x + b.x, a.y + b.y}; }
__device__ __forceinline__ cpx operator-(cpx a, cpx b) { return {a.x - b.x, a.y - b.y}; }
__device__ __forceinline__ cpx cmul(cpx a, cpx b) { return {a.x * b.x - a.y * b.y, a.x * b.y + a.y * b.x}; }
__device__ __forceinline__ cpx mulni(cpx a) { return {a.y, -a.x}; }   // a * (-i)
__device__ __forceinline__ cpx mulpi(cpx a) { return {-a.y, a.x}; }   // a * (+i)

// Bijective XOR bank swizzle: folds bits [7:4] and [11:8] into [3:0].
// Keeps bits >=4 unchanged, so it's invertible; spreads all stage strides
// (1024/128/16/2) and the digit-reversed epilogue gather across bank pairs.
__device__ __forceinline__ int S(int i) { return i ^ ((i >> 4) & 15) ^ ((i >> 8) & 15); }

// 8-point DFT (DIF), W_8 = e^{-2*pi*i/8}
__device__ __forceinline__ void dft8(const cpx* a, cpx* y) {
    cpx b0 = a[0] + a[4], b1 = a[1] + a[5], b2 = a[2] + a[6], b3 = a[3] + a[7];
    cpx b4 = a[0] - a[4], b5 = a[1] - a[5], b6 = a[2] - a[6], b7 = a[3] - a[7];
    cpx c0 = b0 + b2, c1 = b1 + b3, d0 = b0 - b2, d1 = b1 - b3;
    y[0] = c0 + c1;
    y[4] = c0 - c1;
    y[2] = d0 + mulni(d1);
    y[6] = d0 + mulpi(d1);
    cpx e0 = b4;
    cpx e1 = cmul(b5, cpx{RT2O2, -RT2O2});   // * W_8^1
    cpx e2 = mulni(b6);                      // * W_8^2
    cpx e3 = cmul(b7, cpx{-RT2O2, -RT2O2});  // * W_8^3
    cpx f0 = e0 + e2, f1 = e1 + e3, g0 = e0 - e2, g1 = e1 - e3;
    y[1] = f0 + f1;
    y[5] = f0 - f1;
    y[3] = g0 + mulni(g1);
    y[7] = g0 + mulpi(g1);
}

// Storage position of frequency k after DIF stages radix (8,8,8,8,2):
// k = u1 + 8*u2 + 64*u3 + 512*u4 + 4096*u5 lives at
// pos = u1*1024 + u2*128 + u3*16 + u4*2 + u5
__device__ __forceinline__ int posk(int k) {
    return ((k & 7) << 10) | (((k >> 3) & 7) << 7) | (((k >> 6) & 7) << 4) |
           (((k >> 9) & 7) << 1) | ((k >> 12) & 1);
}

__device__ __forceinline__ cpx ldb(const float2* buf, int i) {
    float2 v = buf[S(i)];
    return {v.x, v.y};
}
__device__ __forceinline__ void stb(float2* buf, int i, cpx v) {
    buf[S(i)] = make_float2(v.x, v.y);
}

template <int M>
__device__ __forceinline__ void radix8_stage(float2* buf, int tid) {
#pragma unroll
    for (int h = 0; h < 2; ++h) {
        int tt = tid + h * THREADS;  // 0..1023 butterflies
        int j = tt & (M - 1);
        int blk = tt / M;
        int base = blk * (8 * M) + j;
        cpx a[8];
#pragma unroll
        for (int t = 0; t < 8; ++t) a[t] = ldb(buf, base + t * M);
        cpx y[8];
        dft8(a, y);
        float ang0 = (-2.0f * PI_F / (8.0f * (float)M)) * (float)j;
#pragma unroll
        for (int u = 1; u < 8; ++u) {
            float s, c;
            __sincosf(ang0 * (float)u, &s, &c);
            y[u] = cmul(y[u], cpx{c, s});
        }
#pragma unroll
        for (int u = 0; u < 8; ++u) stb(buf, base + u * M, y[u]);
    }
    __syncthreads();
}

// Two rows packed into one complex FFT: z = row_a + i*row_b.
__global__ __launch_bounds__(THREADS) void dst_fft_kernel(const float* __restrict__ x,
                                                          float* __restrict__ out) {
    __shared__ float2 buf[FFT_N];  // 64 KiB

    const int pair = blockIdx.x;
    const float* __restrict__ xa = x + (size_t)(2 * pair) * FFT_N;
    const float* __restrict__ xb = xa + FFT_N;
    float* __restrict__ ya = out + (size_t)(2 * pair) * FFT_N;
    float* __restrict__ yb = ya + FFT_N;
    const int tid = threadIdx.x;

    // ---- load: sign * Makhoul reorder, pack two rows as (re, im) ----
    // n even: v[n>>1] = x[n]; n odd: v[(16383-n)>>1] = -x[n]
#pragma unroll
    for (int s = 0; s < FFT_N / (4 * THREADS); ++s) {
        int n4 = (s * THREADS + tid) * 4;
        float4 a = *reinterpret_cast<const float4*>(xa + n4);
        float4 b = *reinterpret_cast<const float4*>(xb + n4);
        int h = n4 >> 1;
        stb(buf, h, cpx{a.x, b.x});             // n4   (even)
        stb(buf, h + 1, cpx{a.z, b.z});         // n4+2 (even)
        stb(buf, 8191 - h, cpx{-a.y, -b.y});    // n4+1 (odd)
        stb(buf, 8190 - h, cpx{-a.w, -b.w});    // n4+3 (odd)
    }
    __syncthreads();

    // ---- radix-8 DIF stages ----
    radix8_stage<1024>(buf, tid);
    radix8_stage<128>(buf, tid);
    radix8_stage<16>(buf, tid);

    // ---- fused final stages: radix-8 (m=2, L=16) + radix-2 (m=1), in registers ----
    {
        int base = tid << 4;  // 16 consecutive elements per thread
        cpx a0[8], a1[8];
#pragma unroll
        for (int t = 0; t < 8; ++t) {
            a0[t] = ldb(buf, base + 2 * t);      // j = 0 butterfly
            a1[t] = ldb(buf, base + 2 * t + 1);  // j = 1 butterfly
        }
        cpx w0[8], w1[8];
        dft8(a0, w0);
        dft8(a1, w1);
        // twiddle j=1 outputs by W_16^u
#pragma unroll
        for (int u = 1; u < 8; ++u) {
            float s, c;
            __sincosf((-PI_F / 8.0f) * (float)u, &s, &c);
            w1[u] = cmul(w1[u], cpx{c, s});
        }
        // radix-2 (m=1): pairs (2u, 2u+1)
#pragma unroll
        for (int u = 0; u < 8; ++u) {
            stb(buf, base + 2 * u, w0[u] + w1[u]);
            stb(buf, base + 2 * u + 1, w0[u] - w1[u]);
        }
    }
    __syncthreads();

    // ---- epilogue: unpack two real spectra, expk twiddle, reversed order ----
    // out[o] = Re(A[k] * e^{-i*pi*k/(2N)}), k = N-1-o
    // A[k] = (Z[k] + conj(Z[N-k]))/2 (row a), B[k] = -i(Z[k] - conj(Z[N-k]))/2 (row b)
    const float phi_scale = PI_F / (2.0f * (float)FFT_N);
#pragma unroll
    for (int s = 0; s < FFT_N / THREADS; ++s) {
        int o = s * THREADS + tid;
        int k = (FFT_N - 1) - o;
        int kr = (FFT_N - k) & (FFT_N - 1);
        cpx Z1 = ldb(buf, posk(k));
        cpx Z2 = ldb(buf, posk(kr));
        float Ax = 0.5f * (Z1.x + Z2.x), Ay = 0.5f * (Z1.y - Z2.y);
        float Bx = 0.5f * (Z1.y + Z2.y), By = 0.5f * (Z2.x - Z1.x);
        float sp, cp;
        __sincosf(phi_scale * (float)k, &sp, &cp);
        ya[o] = Ax * cp + Ay * sp;
        yb[o] = Bx * cp + By * sp;
    }
}

extern "C" void kernel_launch(void* const* d_in, const int* in_sizes, int n_in,
                              void* d_out, int out_size, void* d_ws, size_t ws_size,
                              hipStream_t stream) {
    const float* x = (const float*)d_in[0];
    float* out = (float*)d_out;
    const int rows = in_sizes[0] / FFT_N;  // 4096
    dst_fft_kernel<<<rows / 2, THREADS, 0, stream>>>(x, out);
}

// Round 3
// 62.233 us; speedup vs baseline: 3.4729x; 1.0551x over previous
//
#include <hip/hip_runtime.h>

#define FFT_N 8192
#define THREADS 512
#define PI_F 3.14159265358979323846f
#define RT2O2 0.70710678118654752440f

struct cpx { float x, y; };

__device__ __forceinline__ cpx operator+(cpx a, cpx b) { return {a.x + b.x, a.y + b.y}; }
__device__ __forceinline__ cpx operator-(cpx a, cpx b) { return {a.x - b.x, a.y - b.y}; }
__device__ __forceinline__ cpx cmul(cpx a, cpx b) { return {a.x * b.x - a.y * b.y, a.x * b.y + a.y * b.x}; }
__device__ __forceinline__ cpx mulni(cpx a) { return {a.y, -a.x}; }   // * (-i)
__device__ __forceinline__ cpx mulpi(cpx a) { return {-a.y, a.x}; }   // * (+i)

// 16B-unit XOR swizzle (involution): folds unit bits [5:3],[8:6],[11:9] into [2:0]
// so stride-128B patterns (reg-blocked reads/writes, digit-reversed epilogue
// gather) spread across bank sweeps while 16B contiguity (b128) is preserved.
__device__ __forceinline__ int PU(int u) { return u ^ (((u >> 3) ^ (u >> 6) ^ (u >> 9)) & 7); }

__device__ __forceinline__ cpx ldb(const float2* b, int i) {
    float2 v = b[(PU(i >> 1) << 1) | (i & 1)];
    return {v.x, v.y};
}
__device__ __forceinline__ void stb(float2* b, int i, cpx v) {
    b[(PU(i >> 1) << 1) | (i & 1)] = make_float2(v.x, v.y);
}

// In-place 16-point DFT, natural order in/out: z[s] = sum_n z[n] W16^{ns}
__device__ __forceinline__ void dft16(cpx* z) {
    cpx t[4][4];
#pragma unroll
    for (int n0 = 0; n0 < 4; ++n0) {
        cpx a = z[n0], b = z[4 + n0], c = z[8 + n0], d = z[12 + n0];
        cpx apc = a + c, amc = a - c, bpd = b + d, bmd = b - d;
        t[n0][0] = apc + bpd;
        t[n0][1] = amc + mulni(bmd);
        t[n0][2] = apc - bpd;
        t[n0][3] = amc + mulpi(bmd);
    }
    const cpx W1 = {0.92387953251128674f, -0.38268343236508978f};
    const cpx W2 = {RT2O2, -RT2O2};
    const cpx W3 = {0.38268343236508978f, -0.92387953251128674f};
    const cpx W6 = {-RT2O2, -RT2O2};
    const cpx W9 = {-0.92387953251128674f, 0.38268343236508978f};
    t[1][1] = cmul(t[1][1], W1); t[1][2] = cmul(t[1][2], W2); t[1][3] = cmul(t[1][3], W3);
    t[2][1] = cmul(t[2][1], W2); t[2][2] = mulni(t[2][2]);    t[2][3] = cmul(t[2][3], W6);
    t[3][1] = cmul(t[3][1], W3); t[3][2] = cmul(t[3][2], W6); t[3][3] = cmul(t[3][3], W9);
#pragma unroll
    for (int s0 = 0; s0 < 4; ++s0) {
        cpx a = t[0][s0], b = t[1][s0], c = t[2][s0], d = t[3][s0];
        cpx apc = a + c, amc = a - c, bpd = b + d, bmd = b - d;
        z[s0]      = apc + bpd;
        z[s0 + 4]  = amc + mulni(bmd);
        z[s0 + 8]  = apc - bpd;
        z[s0 + 12] = amc + mulpi(bmd);
    }
}

// Apply z[s] *= w1^s for s=1..15 via recurrence (one sincos upstream).
__device__ __forceinline__ void twiddle16(cpx* z, float theta) {
    float s_, c_;
    __sincosf(theta, &s_, &c_);
    cpx w1 = {c_, s_}, w = w1;
#pragma unroll
    for (int s = 1; s < 16; ++s) {
        z[s] = cmul(z[s], w);
        w = cmul(w, w1);
    }
}

// Position of frequency k after DIF radices (16,16,32):
// k = u1 + 16*u2 + 256*k32, k32 = 2s+h  ->  pos = 512*u1 + 32*u2 + 16*h + s
__device__ __forceinline__ int posk(int k) {
    int k32 = k >> 8;
    return ((k & 15) << 9) + (((k >> 4) & 15) << 5) + ((k32 & 1) << 4) + (k32 >> 1);
}

__constant__ float W32R[16] = {
    1.f, 0.98078528040323044f, 0.92387953251128674f, 0.83146961230254524f,
    RT2O2, 0.55557023301960222f, 0.38268343236508978f, 0.19509032201612827f,
    0.f, -0.19509032201612827f, -0.38268343236508978f, -0.55557023301960222f,
    -RT2O2, -0.83146961230254524f, -0.92387953251128674f, -0.98078528040323044f};
__constant__ float W32I[16] = {
    0.f, -0.19509032201612827f, -0.38268343236508978f, -0.55557023301960222f,
    -RT2O2, -0.83146961230254524f, -0.92387953251128674f, -0.98078528040323044f,
    -1.f, -0.98078528040323044f, -0.92387953251128674f, -0.83146961230254524f,
    -RT2O2, -0.55557023301960222f, -0.38268343236508978f, -0.19509032201612827f};

// Two rows packed per complex FFT: z = row_a + i*row_b.
__global__ __launch_bounds__(THREADS) void dst_fft_kernel(const float* __restrict__ x,
                                                          float* __restrict__ out) {
    __shared__ __align__(16) float2 buf[FFT_N];  // 64 KiB

    const int pair = blockIdx.x;
    const float* __restrict__ xa = x + (size_t)(2 * pair) * FFT_N;
    const float* __restrict__ xb = xa + FFT_N;
    float* __restrict__ ya = out + (size_t)(2 * pair) * FFT_N;
    float* __restrict__ yb = ya + FFT_N;
    const int tid = threadIdx.x;

    cpx z[16];

    // ---- load in stage-1 butterfly order (v[tid + 512u]), sign+Makhoul fused ----
    // v[h] = x[2h] (h<4096);  v[h] = -x[16383-2h] (h>=4096)
#pragma unroll
    for (int u = 0; u < 8; ++u) {
        int ia = 2 * tid + (u << 10);
        z[u].x = xa[ia];
        z[u].y = xb[ia];
    }
#pragma unroll
    for (int u = 0; u < 8; ++u) {
        int ia = 8191 - 2 * tid - (u << 10);
        z[8 + u].x = -xa[ia];
        z[8 + u].y = -xb[ia];
    }

    // ---- stage 1: radix-16, stride 512, twiddle W_8192^{tid*s} ----
    dft16(z);
    twiddle16(z, (-2.0f * PI_F / 8192.0f) * (float)tid);
#pragma unroll
    for (int s = 0; s < 16; ++s) stb(buf, tid + (s << 9), z[s]);
    __syncthreads();

    // ---- stage 2: radix-16, stride 32 within length-512 sub-FFTs ----
    const int u1 = tid >> 5, q = tid & 31;
    const int base2 = (u1 << 9) + q;
#pragma unroll
    for (int s = 0; s < 16; ++s) z[s] = ldb(buf, base2 + (s << 5));
    dft16(z);
    twiddle16(z, (-2.0f * PI_F / 512.0f) * (float)q);
#pragma unroll
    for (int s = 0; s < 16; ++s) stb(buf, base2 + (s << 5), z[s]);
    __syncthreads();

    // ---- stage 3: length-32 FFT per consecutive block; 2 threads/block ----
#pragma unroll
    for (int w = 0; w < 8; ++w) {
        float4 v = *reinterpret_cast<const float4*>(&buf[PU((tid << 3) + w) << 1]);
        z[2 * w] = {v.x, v.y};
        z[2 * w + 1] = {v.z, v.w};
    }
    {
        const int h = tid & 1;
        const float sgn = h ? -1.0f : 1.0f;
#pragma unroll
        for (int c = 0; c < 16; ++c) {
            float ox = __shfl_xor(z[c].x, 1);
            float oy = __shfl_xor(z[c].y, 1);
            cpx t = {fmaf(sgn, z[c].x, ox), fmaf(sgn, z[c].y, oy)};
            cpx wc = {h ? W32R[c] : 1.0f, h ? W32I[c] : 0.0f};
            z[c] = cmul(t, wc);  // h=0: e[c]; h=1: o[c]*W32^c
        }
        dft16(z);  // z[s] = X32[2s + h]
    }
#pragma unroll
    for (int w = 0; w < 8; ++w) {
        float4 v = make_float4(z[2 * w].x, z[2 * w].y, z[2 * w + 1].x, z[2 * w + 1].y);
        *reinterpret_cast<float4*>(&buf[PU((tid << 3) + w) << 1]) = v;
    }
    __syncthreads();

    // ---- epilogue: Hermitian unpack pair (k, 8192-k) -> 4 outputs each ----
    const float phi_scale = PI_F / 16384.0f;
#pragma unroll
    for (int it = 0; it < 8; ++it) {
        int p = tid + (it << 9);
        if (p == 0) {
            cpx Z0 = ldb(buf, 0);
            ya[8191] = Z0.x;  // k=0
            yb[8191] = Z0.y;
            cpx Zn = ldb(buf, posk(4096));  // Nyquist, self-paired
            ya[4095] = Zn.x * RT2O2;
            yb[4095] = Zn.y * RT2O2;
        } else {
            cpx Z1 = ldb(buf, posk(p));
            cpx Z2 = ldb(buf, posk(8192 - p));
            float Ax = 0.5f * (Z1.x + Z2.x), Ay = 0.5f * (Z1.y - Z2.y);
            float Bx = 0.5f * (Z1.y + Z2.y), By = 0.5f * (Z2.x - Z1.x);
            float sp, cp;
            __sincosf(phi_scale * (float)p, &sp, &cp);
            ya[8191 - p] = fmaf(Ax, cp, Ay * sp);
            yb[8191 - p] = fmaf(Bx, cp, By * sp);
            ya[p - 1] = fmaf(Ax, sp, -Ay * cp);
            yb[p - 1] = fmaf(Bx, sp, -By * cp);
        }
    }
}

extern "C" void kernel_launch(void* const* d_in, const int* in_sizes, int n_in,
                              void* d_out, int out_size, void* d_ws, size_t ws_size,
                              hipStream_t stream) {
    const float* x = (const float*)d_in[0];
    float* out = (float*)d_out;
    const int rows = in_sizes[0] / FFT_N;  // 4096
    dst_fft_kernel<<<rows / 2, THREADS, 0, stream>>>(x, out);
}

// Round 4
// 58.532 us; speedup vs baseline: 3.6925x; 1.0632x over previous
//
#include <hip/hip_runtime.h>

#define THREADS 256
#define PI_F 3.14159265358979323846f
#define RT2O2 0.70710678118654752440f

struct cpx { float x, y; };

__device__ __forceinline__ cpx operator+(cpx a, cpx b) { return {a.x + b.x, a.y + b.y}; }
__device__ __forceinline__ cpx operator-(cpx a, cpx b) { return {a.x - b.x, a.y - b.y}; }
__device__ __forceinline__ cpx cmul(cpx a, cpx b) { return {a.x * b.x - a.y * b.y, a.x * b.y + a.y * b.x}; }
__device__ __forceinline__ cpx mulni(cpx a) { return {a.y, -a.x}; }   // * (-i)
__device__ __forceinline__ cpx mulpi(cpx a) { return {-a.y, a.x}; }   // * (+i)

// Unified XOR swizzle on cpx index (8B units), bits [3:1] ^= (bits[6:4]^bits[10:8]).
// Bit 0 untouched -> float4 (cpx-pair) alignment preserved. Verified to spread
// each 16-lane group across >=8 distinct bank-pairs for: stage-1 stride-256
// writes, stage-2 stride-16 r/w, stage-3 contiguous-16-per-thread b128 r/w,
// and the digit-reversed epilogue gather.
__device__ __forceinline__ int SW(int i) { return i ^ ((((i >> 4) ^ (i >> 8)) & 7) << 1); }

__device__ __forceinline__ cpx ldb(const float2* b, int i) {
    float2 v = b[SW(i)];
    return {v.x, v.y};
}
__device__ __forceinline__ void stb(float2* b, int i, cpx v) {
    b[SW(i)] = make_float2(v.x, v.y);
}

// In-place 16-point DFT, natural order in/out: z[s] = sum_n z[n] W16^{ns}
__device__ __forceinline__ void dft16(cpx* z) {
    cpx t[4][4];
#pragma unroll
    for (int n0 = 0; n0 < 4; ++n0) {
        cpx a = z[n0], b = z[4 + n0], c = z[8 + n0], d = z[12 + n0];
        cpx apc = a + c, amc = a - c, bpd = b + d, bmd = b - d;
        t[n0][0] = apc + bpd;
        t[n0][1] = amc + mulni(bmd);
        t[n0][2] = apc - bpd;
        t[n0][3] = amc + mulpi(bmd);
    }
    const cpx W1 = {0.92387953251128674f, -0.38268343236508978f};
    const cpx W2 = {RT2O2, -RT2O2};
    const cpx W3 = {0.38268343236508978f, -0.92387953251128674f};
    const cpx W6 = {-RT2O2, -RT2O2};
    const cpx W9 = {-0.92387953251128674f, 0.38268343236508978f};
    t[1][1] = cmul(t[1][1], W1); t[1][2] = cmul(t[1][2], W2); t[1][3] = cmul(t[1][3], W3);
    t[2][1] = cmul(t[2][1], W2); t[2][2] = mulni(t[2][2]);    t[2][3] = cmul(t[2][3], W6);
    t[3][1] = cmul(t[3][1], W3); t[3][2] = cmul(t[3][2], W6); t[3][3] = cmul(t[3][3], W9);
#pragma unroll
    for (int s0 = 0; s0 < 4; ++s0) {
        cpx a = t[0][s0], b = t[1][s0], c = t[2][s0], d = t[3][s0];
        cpx apc = a + c, amc = a - c, bpd = b + d, bmd = b - d;
        z[s0]      = apc + bpd;
        z[s0 + 4]  = amc + mulni(bmd);
        z[s0 + 8]  = apc - bpd;
        z[s0 + 12] = amc + mulpi(bmd);
    }
}

// z[s] *= w1^s for s=1..15 via recurrence (one sincos).
__device__ __forceinline__ void twiddle16(cpx* z, float theta) {
    float s_, c_;
    __sincosf(theta, &s_, &c_);
    cpx w1 = {c_, s_}, w = w1;
#pragma unroll
    for (int s = 1; s < 16; ++s) {
        z[s] = cmul(z[s], w);
        w = cmul(w, w1);
    }
}

// Position of frequency k after DIF radices (16,16,16) on length 4096:
// k = u1 + 16*u2 + 256*u3  ->  pos = 256*u1 + 16*u2 + u3
__device__ __forceinline__ int posk(int k) {
    return ((k & 15) << 8) | (k & 240) | (k >> 8);
}

// One row per block. Real-input DST-II via N/2=4096 complex FFT:
//   v = Makhoul(sign*x)  (real, length 8192)
//   z[m] = v[2m] + i*v[2m+1]; Z = FFT_4096(z)
//   V[k] = Ze[k] + e^{-i pi k/4096} Zo[k]   (real-FFT unpack)
//   out[8191-k] = Re(V[k] e^{-i pi k/16384}); out[k-1] from conj pair.
__global__ __launch_bounds__(THREADS) void dst_fft_kernel(const float* __restrict__ x,
                                                          float* __restrict__ out) {
    __shared__ __align__(16) float2 buf[4096];  // 32 KiB -> 5 blocks/CU

    const int row = blockIdx.x;
    const float* __restrict__ xr = x + (size_t)row * 8192;
    float* __restrict__ yr = out + (size_t)row * 8192;
    const int t = threadIdx.x;

    cpx z[16];

    // ---- load in stage-1 butterfly order: m = t + 256u ----
    // m < 2048:  z[m] = { x[4m],         x[4m+2]       }  (even Makhoul half)
    // m >= 2048: z[m] = {-x[16383-4m],  -x[16381-4m]   }  (odd half, reversed)
#pragma unroll
    for (int u = 0; u < 8; ++u) {
        float4 f = *reinterpret_cast<const float4*>(xr + 4 * t + 1024 * u);
        z[u] = {f.x, f.z};
    }
#pragma unroll
    for (int u = 8; u < 16; ++u) {
        float4 f = *reinterpret_cast<const float4*>(xr + (16380 - 4 * t - 1024 * u));
        z[u] = {-f.w, -f.y};
    }

    // ---- stage 1: radix-16, stride 256, twiddle W_4096^{t*s} ----
    dft16(z);
    twiddle16(z, (-2.0f * PI_F / 4096.0f) * (float)t);
#pragma unroll
    for (int s = 0; s < 16; ++s) stb(buf, t + (s << 8), z[s]);
    __syncthreads();

    // ---- stage 2: 16 sub-FFTs of length 256, radix-16 stride 16 ----
    const int u1 = t >> 4, q = t & 15;
    const int base2 = (u1 << 8) + q;
#pragma unroll
    for (int s = 0; s < 16; ++s) z[s] = ldb(buf, base2 + (s << 4));
    dft16(z);
    twiddle16(z, (-2.0f * PI_F / 256.0f) * (float)q);
#pragma unroll
    for (int s = 0; s < 16; ++s) stb(buf, base2 + (s << 4), z[s]);
    __syncthreads();

    // ---- stage 3: 256 independent 16-point DFTs, thread t -> block t ----
    {
        const int base3 = t << 4;
#pragma unroll
        for (int w = 0; w < 8; ++w) {
            float4 v = *reinterpret_cast<const float4*>(&buf[SW(base3 + 2 * w)]);
            z[2 * w] = {v.x, v.y};
            z[2 * w + 1] = {v.z, v.w};
        }
        dft16(z);
#pragma unroll
        for (int w = 0; w < 8; ++w) {
            *reinterpret_cast<float4*>(&buf[SW(base3 + 2 * w)]) =
                make_float4(z[2 * w].x, z[2 * w].y, z[2 * w + 1].x, z[2 * w + 1].y);
        }
    }
    __syncthreads();

    // ---- epilogue: real-FFT unpack + DST twiddle, k = t + 256*it ----
    float s4, c4, s1, c1;
    __sincosf((PI_F / 4096.0f) * (float)t, &s4, &c4);
    __sincosf((PI_F / 16384.0f) * (float)t, &s1, &c1);
    cpx w4 = {c4, -s4};  // e^{-i pi k/4096}
    cpx w1 = {c1, s1};   // {cos, sin}(pi k/16384)
    const cpx st4 = {0.98078528040323044f, -0.19509032201612827f};  // e^{-i pi/16}
    const cpx st1 = {0.99879545620517239f, 0.049067674327418015f};  // +pi/64 rot
#pragma unroll
    for (int it = 0; it < 16; ++it) {
        const int k = t + (it << 8);
        if (k == 0) {
            cpx Z0 = ldb(buf, 0);
            yr[8191] = Z0.x + Z0.y;            // k = 0:    V[0] = ReZ0 + ImZ0
            yr[4095] = (Z0.x - Z0.y) * RT2O2;  // k = 4096: V = ReZ0 - ImZ0, *cos(pi/4)
        } else {
            cpx Z1 = ldb(buf, posk(k));
            cpx Z2 = ldb(buf, posk(4096 - k));
            float Zex = 0.5f * (Z1.x + Z2.x), Zey = 0.5f * (Z1.y - Z2.y);
            float Zox = 0.5f * (Z1.y + Z2.y), Zoy = 0.5f * (Z2.x - Z1.x);
            float Vx = Zex + w4.x * Zox - w4.y * Zoy;
            float Vy = Zey + w4.x * Zoy + w4.y * Zox;
            yr[8191 - k] = fmaf(Vx, w1.x, Vy * w1.y);   // Vx*cos + Vy*sin
            yr[k - 1]    = fmaf(Vx, w1.y, -Vy * w1.x);  // Vx*sin - Vy*cos
        }
        w4 = cmul(w4, st4);
        w1 = cmul(w1, st1);
    }
}

extern "C" void kernel_launch(void* const* d_in, const int* in_sizes, int n_in,
                              void* d_out, int out_size, void* d_ws, size_t ws_size,
                              hipStream_t stream) {
    const float* x = (const float*)d_in[0];
    float* out = (float*)d_out;
    const int rows = in_sizes[0] / 8192;  // 4096
    dst_fft_kernel<<<rows, THREADS, 0, stream>>>(x, out);
}